// Round 8
// baseline (43.074 us; speedup 1.0000x reference)
//
#include <hip/hip_runtime.h>

// TMPI tiled renderer: composite 512 depth-sorted 144x144 tiles into a
// 656x656 buffer with per-pixel transmittance; return cropped 512x512x3.
constexpr int TILE   = 128;
constexpr int PAD    = 8;
constexpr int HP     = TILE + 2 * PAD;  // 144
constexpr int P      = HP * HP;         // 20736
constexpr int S      = 512;
constexpr int OUTW   = 512;
constexpr int OUTP   = OUTW * OUTW;
constexpr int NSEG   = 8;               // waves per block
constexpr int NCHUNK = OUTW / 64;       // 8 column chunks
constexpr int BAND   = 8;               // rows per block (one per wave)
constexpr int CAP    = 128;             // planes kept per band list
constexpr int GROUP  = 8;               // early-exit check granularity
constexpr float TEPS = 1e-3f;           // transmittance cutoff (err <= TEPS)

// ---------------------------------------------------------------------------
// Kernel 1: stable depth sort (O(S^2) rank) + metadata pack.
// meta[rank] = { sy, sx, i*P (sigma base), i*3*P (rgb base) }
// ---------------------------------------------------------------------------
__global__ __launch_bounds__(512) void sort_planes_kernel(
    const float* __restrict__ depth,
    const int*   __restrict__ sx,
    const int*   __restrict__ sy,
    int4*        __restrict__ meta)
{
    __shared__ float sd[S];
    const int i = threadIdx.x;
    sd[i] = depth[i];
    __syncthreads();

    const float di = sd[i];
    int rank = 0;
#pragma unroll 8
    for (int j = 0; j < S; ++j) {
        const float dj = sd[j];
        rank += (dj < di) || (dj == di && j < i);   // stable tie-break
    }
    meta[rank] = make_int4(sy[i], sx[i], i * P, i * 3 * P);
}

// ---------------------------------------------------------------------------
// Software-pipeline staging group: raw loads + VALU-only coverage mask.
// All member indices are static after full unroll (no scratch spill).
// ---------------------------------------------------------------------------
struct Grp {
    float s[GROUP];   // raw sigma loads
    float m[GROUP];   // coverage mask (0/1), VALU-only -> no waitcnt at issue
    float r[GROUP], g[GROUP], b[GROUP];   // raw rgb loads
};

__device__ __forceinline__ void issue_grp(
    Grp& gb, const int4* __restrict__ slist, int k, int yb, int xb,
    const float* __restrict__ sigma, const float* __restrict__ rgb)
{
#pragma unroll
    for (int u = 0; u < GROUP; ++u) {
        const int4 e = slist[k + u];            // broadcast LDS read
        const int yy = yb - e.x;
        const int xx = xb - e.y;
        const bool c = ((unsigned)yy < (unsigned)HP) &
                       ((unsigned)xx < (unsigned)HP);
        const int yc = min(max(yy, 0), HP - 1); // v_med3 clamps (safe addr)
        const int xc = min(max(xx, 0), HP - 1);
        const int o  = yc * HP + xc;
        gb.m[u] = c ? 1.0f : 0.0f;              // no load consumed here
        gb.s[u] = sigma[e.z + o];
        const int pr = e.w + o;
        gb.r[u] = rgb[pr];
        gb.g[u] = rgb[pr + P];
        gb.b[u] = rgb[pr + 2 * P];
    }
}

__device__ __forceinline__ void accum_grp(
    const Grp& gb, float& trans, float& ar, float& ag, float& ab)
{
#pragma unroll
    for (int u = 0; u < GROUP; ++u) {
        const float sg  = gb.s[u] * gb.m[u];    // masked sigma
        const float wgt = sg * trans;
        ar = fmaf(gb.r[u], wgt, ar);
        ag = fmaf(gb.g[u], wgt, ag);
        ab = fmaf(gb.b[u], wgt, ab);
        trans *= (1.0f - sg);
    }
}

// ---------------------------------------------------------------------------
// Kernel 2: fused build + composite, software-pipelined.
// Block = 64 cols x 8 rows (512 threads, 8 waves; wave w owns row Y0+w).
//  Phase A: ballot-compact the 512 sorted planes to this band -> LDS list.
//  Phase B: per-wave front-to-back composite; group k+1's loads issue
//           BEFORE group k is accumulated, so the early-exit check overlaps
//           the next group's memory latency instead of gating it.
//  NOTE: Phase B is guarded by padded > 0 — corner bands can have ZERO
//  covering planes (P ~ 2% per corner block with this seed); reading the
//  uninitialized LDS list there was round 7's GPU fault.
// ---------------------------------------------------------------------------
__global__ __launch_bounds__(512) void fused_composite_kernel(
    const float* __restrict__ rgb,     // [S][3][P]
    const float* __restrict__ sigma,   // [S][P]
    const int4*  __restrict__ meta,    // [S] depth-sorted
    float*       __restrict__ out)     // [3][512][512]
{
    __shared__ int4 slist[CAP];
    __shared__ int  cnt[NSEG];

    const int tid  = threadIdx.x;
    const int w    = tid >> 6;
    const int lane = tid & 63;
    const int X0   = blockIdx.x * 64;          // output col base
    const int Y0   = blockIdx.y * BAND;        // output row base

    // --- Phase A: band compaction (thread t inspects sorted plane t) ---
    const int4 m = meta[tid];
    const bool cov =
        ((unsigned)(Y0 + PAD + BAND - 1 - m.x) < (unsigned)(HP + BAND - 1)) &&
        ((unsigned)(X0 + 71 - m.y) < 207u);
    const unsigned long long mask = __ballot(cov);
    const int pre = __popcll(mask & ((1ull << lane) - 1ull));
    if (lane == 0) cnt[w] = __popcll(mask);
    __syncthreads();

    int off = 0, nc = 0;
#pragma unroll
    for (int i = 0; i < NSEG; ++i) {
        const int c = cnt[i];
        off += (i < w) ? c : 0;
        nc  += c;
    }
    const int padded = min((nc + GROUP - 1) & ~(GROUP - 1), CAP);
    if (cov) {
        const int idx = off + pre;
        if (idx < CAP) slist[idx] = m;          // truncation: trans ~ 0 there
    }
    // sentinel: far OOB -> mask 0, clamped addresses stay in-bounds
    if (tid >= nc && tid < padded) slist[tid] = make_int4(-100000, -100000, 0, 0);
    __syncthreads();

    // --- Phase B: pipelined per-wave composite of row Y0+w ---
    const int row = Y0 + w;
    const int yb  = row + PAD;
    const int xb  = X0 + PAD + lane;

    float trans = 1.0f, ar = 0.0f, ag = 0.0f, ab = 0.0f;

    if (padded > 0) {                           // empty band -> zeros
        Grp A, B;
        issue_grp(A, slist, 0, yb, xb, sigma, rgb);
        int k = 0;
        for (;;) {
            bool last = (k + GROUP >= padded);
            if (!last) issue_grp(B, slist, k + GROUP, yb, xb, sigma, rgb);
            accum_grp(A, trans, ar, ag, ab);
            k += GROUP;
            if (last || __all(trans < TEPS)) break;

            last = (k + GROUP >= padded);
            if (!last) issue_grp(A, slist, k + GROUP, yb, xb, sigma, rgb);
            accum_grp(B, trans, ar, ag, ab);
            k += GROUP;
            if (last || __all(trans < TEPS)) break;
        }
    }

    const int o = row * OUTW + X0 + lane;
    out[o]            = ar;
    out[o + OUTP]     = ag;
    out[o + 2 * OUTP] = ab;
}

// ---------------------------------------------------------------------------
extern "C" void kernel_launch(void* const* d_in, const int* in_sizes, int n_in,
                              void* d_out, int out_size, void* d_ws, size_t ws_size,
                              hipStream_t stream)
{
    const float* tgt_rgb   = (const float*)d_in[0];  // (1,S,3,P)
    const float* tgt_sigma = (const float*)d_in[1];  // (1,S,P)
    const float* mpi_depth = (const float*)d_in[2];  // (1,S)
    const int*   sx        = (const int*)d_in[3];    // (1,S) col offsets
    const int*   sy        = (const int*)d_in[4];    // (1,S) row offsets
    float*       out       = (float*)d_out;          // (1,3,512,512)
    int4*        meta      = (int4*)d_ws;            // 512 * 16 B

    sort_planes_kernel<<<1, S, 0, stream>>>(mpi_depth, sx, sy, meta);

    dim3 grid(NCHUNK, OUTW / BAND);              // (8, 64) = 512 blocks
    fused_composite_kernel<<<grid, 512, 0, stream>>>(tgt_rgb, tgt_sigma,
                                                     meta, out);
}

// Round 9
// 43.048 us; speedup vs baseline: 1.0006x; 1.0006x over previous
//
#include <hip/hip_runtime.h>

// TMPI tiled renderer: composite 512 depth-sorted 144x144 tiles into a
// 656x656 buffer with per-pixel transmittance; return cropped 512x512x3.
constexpr int TILE   = 128;
constexpr int PAD    = 8;
constexpr int HP     = TILE + 2 * PAD;  // 144
constexpr int P      = HP * HP;         // 20736
constexpr int S      = 512;
constexpr int OUTW   = 512;
constexpr int OUTP   = OUTW * OUTW;
constexpr int NSEG   = 8;               // waves per block
constexpr int NCHUNK = OUTW / 64;       // 8 column chunks
constexpr int BAND   = 8;               // rows per block (one per wave)
constexpr int CAP    = 128;             // planes kept per band list
constexpr int GROUP  = 8;               // group size / exit granularity
constexpr float TEPS = 1e-3f;           // transmittance cutoff (err <= TEPS)
constexpr float WEPS = 1e-4f;           // per-plane weight cutoff for rgb

// ---------------------------------------------------------------------------
// Kernel 1: stable depth sort (O(S^2) rank) + metadata pack.
// meta[rank] = { sy, sx, i*P (sigma base), i*3*P (rgb base) }
// ---------------------------------------------------------------------------
__global__ __launch_bounds__(512) void sort_planes_kernel(
    const float* __restrict__ depth,
    const int*   __restrict__ sx,
    const int*   __restrict__ sy,
    int4*        __restrict__ meta)
{
    __shared__ float sd[S];
    const int i = threadIdx.x;
    sd[i] = depth[i];
    __syncthreads();

    const float di = sd[i];
    int rank = 0;
#pragma unroll 8
    for (int j = 0; j < S; ++j) {
        const float dj = sd[j];
        rank += (dj < di) || (dj == di && j < i);   // stable tie-break
    }
    meta[rank] = make_int4(sy[i], sx[i], i * P, i * 3 * P);
}

// ---------------------------------------------------------------------------
// Kernel 2: fused build + composite, lockstep bands + sigma-gated rgb.
// Block = 64 cols x 8 rows (512 threads, 8 waves; wave w owns row Y0+w).
//  Phase A: ballot-compact the 512 sorted planes to this band -> LDS list.
//  Phase B: groups of 8 planes. Per group: load 8 sigmas, compute weights
//           and the trans chain, then load the 24 rgb values ONLY if some
//           lane has weight > WEPS (wave-uniform branch — tail groups skip
//           3/4 of their bytes). All 8 waves advance in lockstep
//           (__syncthreads_and exit vote), so the band's 8 rows of each
//           plane (4.6 KB contiguous span) reach DRAM together.
//           Finished waves load nothing while waiting for the block.
// ---------------------------------------------------------------------------
__global__ __launch_bounds__(512) void fused_composite_kernel(
    const float* __restrict__ rgb,     // [S][3][P]
    const float* __restrict__ sigma,   // [S][P]
    const int4*  __restrict__ meta,    // [S] depth-sorted
    float*       __restrict__ out)     // [3][512][512]
{
    __shared__ int4 slist[CAP];
    __shared__ int  cnt[NSEG];

    const int tid  = threadIdx.x;
    const int w    = tid >> 6;
    const int lane = tid & 63;
    const int X0   = blockIdx.x * 64;          // output col base
    const int Y0   = blockIdx.y * BAND;        // output row base

    // --- Phase A: band compaction (thread t inspects sorted plane t) ---
    const int4 m = meta[tid];
    const bool cov =
        ((unsigned)(Y0 + PAD + BAND - 1 - m.x) < (unsigned)(HP + BAND - 1)) &&
        ((unsigned)(X0 + 71 - m.y) < 207u);
    const unsigned long long bmask = __ballot(cov);
    const int pre = __popcll(bmask & ((1ull << lane) - 1ull));
    if (lane == 0) cnt[w] = __popcll(bmask);
    __syncthreads();

    int off = 0, nc = 0;
#pragma unroll
    for (int i = 0; i < NSEG; ++i) {
        const int c = cnt[i];
        off += (i < w) ? c : 0;
        nc  += c;
    }
    const int padded = min((nc + GROUP - 1) & ~(GROUP - 1), CAP);
    if (cov) {
        const int idx = off + pre;
        if (idx < CAP) slist[idx] = m;          // truncation: trans ~ 0 there
    }
    // sentinel: far OOB -> mask 0, clamped addresses stay in-bounds
    if (tid >= nc && tid < padded) slist[tid] = make_int4(-100000, -100000, 0, 0);
    __syncthreads();

    // --- Phase B: lockstep per-group composite of row Y0+w ---
    const int row = Y0 + w;
    const int yb  = row + PAD;
    const int xb  = X0 + PAD + lane;

    float trans = 1.0f, ar = 0.0f, ag = 0.0f, ab = 0.0f;
    bool wave_done = false;

    for (int k = 0; k < padded; k += GROUP) {
        if (!wave_done) {
            // sigma phase: 8 loads + masks + rgb addresses
            float sg[GROUP], mm[GROUP];
            int   pr[GROUP];
#pragma unroll
            for (int u = 0; u < GROUP; ++u) {
                const int4 e = slist[k + u];            // broadcast LDS read
                const int yy = yb - e.x;
                const int xx = xb - e.y;
                const bool c = ((unsigned)yy < (unsigned)HP) &
                               ((unsigned)xx < (unsigned)HP);
                const int yc = min(max(yy, 0), HP - 1); // v_med3 clamps
                const int xc = min(max(xx, 0), HP - 1);
                const int o  = yc * HP + xc;
                mm[u] = c ? 1.0f : 0.0f;
                sg[u] = sigma[e.z + o];
                pr[u] = e.w + o;
            }
            // weight chain (serial in trans, VALU only)
            float wt[GROUP], t = trans, wmax = 0.0f;
#pragma unroll
            for (int u = 0; u < GROUP; ++u) {
                const float s = sg[u] * mm[u];
                wt[u] = s * t;
                t *= (1.0f - s);
                wmax = fmaxf(wmax, wt[u]);
            }
            // rgb phase, only if some lane's weight matters (wave-uniform)
            if (__any(wmax > WEPS)) {
                float r[GROUP], g[GROUP], b[GROUP];
#pragma unroll
                for (int u = 0; u < GROUP; ++u) {
                    r[u] = rgb[pr[u]];
                    g[u] = rgb[pr[u] + P];
                    b[u] = rgb[pr[u] + 2 * P];
                }
#pragma unroll
                for (int u = 0; u < GROUP; ++u) {
                    ar = fmaf(r[u], wt[u], ar);
                    ag = fmaf(g[u], wt[u], ag);
                    ab = fmaf(b[u], wt[u], ab);
                }
            }
            trans = t;
            wave_done = __all(trans < TEPS);
        }
        // block-wide lockstep exit vote (uniform: all threads reach this)
        if (__syncthreads_and(wave_done ? 1 : 0)) break;
    }

    const int o = row * OUTW + X0 + lane;
    out[o]            = ar;
    out[o + OUTP]     = ag;
    out[o + 2 * OUTP] = ab;
}

// ---------------------------------------------------------------------------
extern "C" void kernel_launch(void* const* d_in, const int* in_sizes, int n_in,
                              void* d_out, int out_size, void* d_ws, size_t ws_size,
                              hipStream_t stream)
{
    const float* tgt_rgb   = (const float*)d_in[0];  // (1,S,3,P)
    const float* tgt_sigma = (const float*)d_in[1];  // (1,S,P)
    const float* mpi_depth = (const float*)d_in[2];  // (1,S)
    const int*   sx        = (const int*)d_in[3];    // (1,S) col offsets
    const int*   sy        = (const int*)d_in[4];    // (1,S) row offsets
    float*       out       = (float*)d_out;          // (1,3,512,512)
    int4*        meta      = (int4*)d_ws;            // 512 * 16 B

    sort_planes_kernel<<<1, S, 0, stream>>>(mpi_depth, sx, sy, meta);

    dim3 grid(NCHUNK, OUTW / BAND);              // (8, 64) = 512 blocks
    fused_composite_kernel<<<grid, 512, 0, stream>>>(tgt_rgb, tgt_sigma,
                                                     meta, out);
}